// Round 11
// baseline (224.774 us; speedup 1.0000x reference)
//
#include <hip/hip_runtime.h>

#define BATCH 512
#define SEQ   512
#define VOCAB 1000
#define EMB   100
#define UNITS 64

typedef _Float16 h8 __attribute__((ext_vector_type(8)));
typedef _Float16 h2 __attribute__((ext_vector_type(2)));
typedef float    f4 __attribute__((ext_vector_type(4)));
typedef int      i4 __attribute__((ext_vector_type(4)));

// ---------------------------------------------------------------------------
// Kernel 1: P[v][u] = sum_d emb[v][d] * Wxh[d][u] + b[u]   (VOCAB x UNITS)
// ---------------------------------------------------------------------------
__global__ __launch_bounds__(64) void proj_kernel(
    const float* __restrict__ emb, const float* __restrict__ Wxh,
    const float* __restrict__ bias, float* __restrict__ P) {
  const int v = blockIdx.x;
  const int u = threadIdx.x;
  const float* e = emb + v * EMB;
  float acc = bias[u];
#pragma unroll 5
  for (int d = 0; d < EMB; ++d) acc += e[d] * Wxh[d * UNITS + u];
  P[v * UNITS + u] = acc;
}

// ---------------------------------------------------------------------------
// Kernel 2: sequential scan, one wave per batch row.
//   h <- tanh(x_t + h @ Whh),  s(1x64) = h(1x64) @ Whh(64x64) via MFMA.
//
// Evidence trail: readlane broadcast ~13 cyc/unit (r4==r8); LDS broadcast
// floor ~550-650 cyc/step whether compiler- (r5: 571) or hand-scheduled
// (r10: 645) — DS service of 256 B + write->read turnaround is structural.
// This version lets the MFMA systolic array do the all-to-all:
//   - 4 N-tiles x 2 K-chained mfma_f32_16x16x32_f16; A = h replicated
//     across all 16 M rows => D regs replicated => results in ALL lanes.
//   - column permutation unit = 4*col + tile => lane c owns units 4c..4c+3
//     (contiguous): x_t loads as one dwordx4, state packs into 2 dwords.
//   - A-fragment rebuild via 8 INDEPENDENT ds_bpermute_b32 (register
//     cross-lane, no LDS round trip, no barriers).
// State h and Whh in f16 (RTN), x and accumulate fp32.
// ---------------------------------------------------------------------------
__global__ __launch_bounds__(64)
__attribute__((amdgpu_waves_per_eu(1, 1)))
void scan_kernel(
    const int* __restrict__ tok, const float* __restrict__ P,
    const float* __restrict__ Whh, const float* __restrict__ Wout,
    const float* __restrict__ bout, float* __restrict__ out) {
  const int row  = blockIdx.x;
  const int lane = threadIdx.x;
  const int c    = lane & 15;   // tile column
  const int q    = lane >> 4;   // quad (k-group)

  // B fragments: bf[t][kc][j] = Whh[kc*32 + q*8 + j][4c + t]  (f16).
  // B-layout for 16x16x32: B[k][n], n = lane&15, k = quad*8 + j.
  h8 bf[4][2];
#pragma unroll
  for (int t = 0; t < 4; ++t)
#pragma unroll
    for (int kc = 0; kc < 2; ++kc) {
      h8 b;
#pragma unroll
      for (int j = 0; j < 8; ++j)
        b[j] = (_Float16)Whh[(kc * 32 + q * 8 + j) * UNITS + 4 * c + t];
      asm volatile("" : "+v"(b));  // keep resident; no remat into the loop
      bf[t][kc] = b;
    }

  // Tokens, pre-scaled by UNITS (coalesced loads).
  int tokv[SEQ / 64];
  const int* trow = tok + (long)row * SEQ;
#pragma unroll
  for (int ch = 0; ch < SEQ / 64; ++ch) {
    int t = trow[ch * 64 + lane] * UNITS;
    asm volatile("" : "+v"(t));
    tokv[ch] = t;
  }

  // bpermute source byte-addresses (4 * source_lane), loop-invariant.
  // K1 (units q*8..q*8+7)  -> source lanes 2q, 2q+1
  // K2 (units 32+q*8..+7)  -> source lanes 8+2q, 9+2q
  const int ad0 = (2 * q) << 2, ad1 = (2 * q + 1) << 2;
  const int ad2 = (8 + 2 * q) << 2, ad3 = (9 + 2 * q) << 2;

  // Packed f16 state: d0 = (h[4c], h[4c+1]), d1 = (h[4c+2], h[4c+3]).
  int d0 = 0, d1 = 0;
  float h0 = 0.f, h1 = 0.f, h2v = 0.f, h3 = 0.f;  // fp32 copies (epilogue)

  // Prefetch x for t=0: av[t] = xproj[4c + t] (one dwordx4).
  int tk0 = __builtin_amdgcn_readlane(tokv[0], 0);
  f4 av = *(const f4*)&P[(long)tk0 + 4 * c];

#pragma unroll
  for (int ch = 0; ch < SEQ / 64; ++ch) {
#pragma unroll 2
    for (int tt = 0; tt < 64; ++tt) {
      f4 a_cur = av;
      // Prefetch next timestep's x row (consumed a full step later).
      int ntt = (tt + 1) & 63;
      int tkn = __builtin_amdgcn_readlane(tokv[ch], ntt);
      av = *(const f4*)&P[(long)tkn + 4 * c];

      // ---- A-fragment rebuild: 8 independent bpermutes ----
      i4 w1, w2;
      w1.x = __builtin_amdgcn_ds_bpermute(ad0, d0);
      w1.y = __builtin_amdgcn_ds_bpermute(ad0, d1);
      w1.z = __builtin_amdgcn_ds_bpermute(ad1, d0);
      w1.w = __builtin_amdgcn_ds_bpermute(ad1, d1);
      w2.x = __builtin_amdgcn_ds_bpermute(ad2, d0);
      w2.y = __builtin_amdgcn_ds_bpermute(ad2, d1);
      w2.z = __builtin_amdgcn_ds_bpermute(ad3, d0);
      w2.w = __builtin_amdgcn_ds_bpermute(ad3, d1);
      h8 A1 = __builtin_bit_cast(h8, w1);   // A[k = q*8+j], k in [0,32)
      h8 A2 = __builtin_bit_cast(h8, w2);   // k in [32,64)

      // ---- 4 tile-chains of 2 K-MFMAs, C = x (replicated rows) ----
      f4 C0 = {a_cur.x, a_cur.x, a_cur.x, a_cur.x};
      f4 C1 = {a_cur.y, a_cur.y, a_cur.y, a_cur.y};
      f4 C2 = {a_cur.z, a_cur.z, a_cur.z, a_cur.z};
      f4 C3 = {a_cur.w, a_cur.w, a_cur.w, a_cur.w};
      f4 D0 = __builtin_amdgcn_mfma_f32_16x16x32_f16(A1, bf[0][0], C0, 0, 0, 0);
      f4 D1 = __builtin_amdgcn_mfma_f32_16x16x32_f16(A1, bf[1][0], C1, 0, 0, 0);
      f4 D2 = __builtin_amdgcn_mfma_f32_16x16x32_f16(A1, bf[2][0], C2, 0, 0, 0);
      f4 D3 = __builtin_amdgcn_mfma_f32_16x16x32_f16(A1, bf[3][0], C3, 0, 0, 0);
      D0 = __builtin_amdgcn_mfma_f32_16x16x32_f16(A2, bf[0][1], D0, 0, 0, 0);
      D1 = __builtin_amdgcn_mfma_f32_16x16x32_f16(A2, bf[1][1], D1, 0, 0, 0);
      D2 = __builtin_amdgcn_mfma_f32_16x16x32_f16(A2, bf[2][1], D2, 0, 0, 0);
      D3 = __builtin_amdgcn_mfma_f32_16x16x32_f16(A2, bf[3][1], D3, 0, 0, 0);

      // s for this lane's 4 units (all D regs equal; take reg 0):
      // s[4c+t] = D_t[0].
      float s0 = D0.x, s1 = D1.x, s2 = D2.x, s3 = D3.x;

      // tanh(s) = 1 - 2/(exp(2s)+1), 4 independent chains.
      float e0 = __expf(2.f * s0), e1 = __expf(2.f * s1);
      float e2 = __expf(2.f * s2), e3 = __expf(2.f * s3);
      h0 = 1.f - 2.f / (e0 + 1.f);
      h1 = 1.f - 2.f / (e1 + 1.f);
      h2v = 1.f - 2.f / (e2 + 1.f);
      h3 = 1.f - 2.f / (e3 + 1.f);

      // Pack new state to f16 pairs (RTN via scalar cvt + pack).
      h2 p0, p1;
      p0.x = (_Float16)h0;  p0.y = (_Float16)h1;
      p1.x = (_Float16)h2v; p1.y = (_Float16)h3;
      d0 = __builtin_bit_cast(int, p0);
      d1 = __builtin_bit_cast(int, p1);
    }
    if (ch + 1 < SEQ / 64) {
      int tkb = __builtin_amdgcn_readlane(tokv[ch + 1], 0);
      av = *(const f4*)&P[(long)tkb + 4 * c];
    }
  }

  // out[row] = sigmoid(sum_u h[u]*Wout[u] + bout).
  // Lane c holds units 4c..4c+3 (replicated across quads).
  f4 wo = *(const f4*)&Wout[4 * c];
  float p = h0 * wo.x + h1 * wo.y + h2v * wo.z + h3 * wo.w;
#pragma unroll
  for (int off = 8; off > 0; off >>= 1) p += __shfl_xor(p, off);
  if (lane == 0) out[row] = 1.f / (1.f + __expf(-(p + bout[0])));
}

extern "C" void kernel_launch(void* const* d_in, const int* in_sizes, int n_in,
                              void* d_out, int out_size, void* d_ws, size_t ws_size,
                              hipStream_t stream) {
  const int*   tok  = (const int*)  d_in[0];  // [BATCH, SEQ] int32
  const float* emb  = (const float*)d_in[1];  // [VOCAB, EMB]
  const float* Wxh  = (const float*)d_in[2];  // [EMB, UNITS]
  const float* Whh  = (const float*)d_in[3];  // [UNITS, UNITS]
  const float* bias = (const float*)d_in[4];  // [UNITS]
  const float* Wout = (const float*)d_in[5];  // [UNITS, 1]
  const float* bout = (const float*)d_in[6];  // [1]
  float* out = (float*)d_out;                 // [BATCH, 1] fp32

  float* P = (float*)d_ws;                    // VOCAB*UNITS fp32 = 256 KB

  proj_kernel<<<VOCAB, 64, 0, stream>>>(emb, Wxh, bias, P);
  scan_kernel<<<BATCH, 64, 0, stream>>>(tok, P, Whh, Wout, bout, out);
}